// Round 9
// baseline (445.802 us; speedup 1.0000x reference)
//
#include <hip/hip_runtime.h>

// Sparse 3D conv (K=3, stride=2, pad=1), dense output, direct per-point scatter.
// Persistent grid (2048 blocks), one wave per point-PAIR iteration:
// 64 lanes = 64 output channels, two independent candidate streams for ILP.
// Inputs: features [N,32] f32, W [3,3,3,32,64] f32, coors [N,4] i32 (b,z,y,x).
// Output: [B,64,64,64,64] f32 flat (memset to 0, then posted atomic adds).
// ws: [ W_t 27*64*32 f32 ]  (~221 KB)

#define CIN   32
#define COUT  64
#define OUTD  64
#define NBLK  2048
#define NPTS  128

// Valid (k, o) options along one axis: o = (p+1-k)/2, parity-matched, 0<=o<64.
__device__ __forceinline__ int axis_opts(int p, int* k, int* o) {
    int cnt = 0;
    const int kp = (p + 1) & 1;          // smallest parity-matching k
    const int o0 = (p + 1 - kp) >> 1;    // >= 0 always
    if (o0 < OUTD) { k[cnt] = kp; o[cnt] = o0; ++cnt; }
    if (kp == 0) {                       // k=2 shares parity with k=0
        const int o1 = o0 - 1;
        if (o1 >= 0) { k[cnt] = 2; o[cnt] = o1; ++cnt; }
    }
    return cnt;
}

__device__ __forceinline__ int enum_cands(const int4 c, int* kk, int* fl) {
    int kz[2], oz[2], ky[2], oy[2], kx[2], ox[2];
    const int nz = axis_opts(c.y, kz, oz);
    const int ny = axis_opts(c.z, ky, oy);
    const int nx = axis_opts(c.w, kx, ox);
    int n = 0;
    for (int az = 0; az < nz; ++az)
    for (int ay = 0; ay < ny; ++ay)
    for (int ax = 0; ax < nx; ++ax) {
        kk[n] = (kz[az] * 3 + ky[ay]) * 3 + kx[ax];
        fl[n] = (((c.x * OUTD + oz[az]) * OUTD + oy[ay]) * OUTD + ox[ax]);
        ++n;
    }
    return n;
}

// ---------- W transpose: [27][32][64] -> [27][64][32], f32 ----------
__global__ void conv_w_t(const float* __restrict__ W, float* __restrict__ wsW)
{
    const int k = blockIdx.x;            // 27 blocks
    for (int i = threadIdx.x; i < CIN * COUT; i += 256) {
        const int c = i >> 6, ch = i & 63;     // read coalesced over i
        wsW[(k << 11) + (ch << 5) + c] = W[(k << 11) + i];
    }
}

// ---------- scatter: persistent waves, 2 points in flight per wave ----------
__global__ __launch_bounds__(256) void scatter5(
    const float* __restrict__ feats, const float* __restrict__ wsW,
    const int4* __restrict__ coors, float* __restrict__ out,
    int N, int totWaves)
{
    const int ch = threadIdx.x & 63;
    const int wv = threadIdx.x >> 6;
    const int gwave = blockIdx.x * 4 + wv;

    for (int i0 = gwave; i0 < N; i0 += 2 * totWaves) {
        const int i1 = i0 + totWaves;
        const bool has1 = (i1 < N);
        const int i1c = has1 ? i1 : i0;

        const int4 c0 = coors[i0];           // wave-uniform loads
        const int4 c1 = coors[i1c];

        const float4* fp0 = (const float4*)(feats + (size_t)i0 * CIN);
        const float4* fp1 = (const float4*)(feats + (size_t)i1c * CIN);
        float4 f0[8], f1[8];
        #pragma unroll
        for (int q = 0; q < 8; ++q) f0[q] = fp0[q];
        #pragma unroll
        for (int q = 0; q < 8; ++q) f1[q] = fp1[q];

        int kk0[8], fl0[8], kk1[8], fl1[8];
        const int n0 = enum_cands(c0, kk0, fl0);
        const int n1 = has1 ? enum_cands(c1, kk1, fl1) : 0;

        const int nmax = n0 > n1 ? n0 : n1;
        for (int t = 0; t < nmax; ++t) {
            const bool v0 = t < n0, v1 = t < n1;
            const int a0 = v0 ? t : 0;
            const int a1 = v1 ? t : 0;
            const float4* wp0 = (const float4*)(wsW + (kk0[a0] << 11) + (ch << 5));
            const float4* wp1 = (const float4*)(wsW + (kk1[a1] << 11) + (ch << 5));

            // two independent load->FMA chains, interleaved for ILP
            float x0 = 0.f, x1 = 0.f, x2 = 0.f, x3 = 0.f;   // stream 0
            float y0 = 0.f, y1 = 0.f, y2 = 0.f, y3 = 0.f;   // stream 1
            #pragma unroll
            for (int q = 0; q < 8; ++q) {
                const float4 wq0 = wp0[q];
                const float4 wq1 = wp1[q];
                const float4 a = f0[q], b = f1[q];
                x0 += a.x * wq0.x;  y0 += b.x * wq1.x;
                x1 += a.y * wq0.y;  y1 += b.y * wq1.y;
                x2 += a.z * wq0.z;  y2 += b.z * wq1.z;
                x3 += a.w * wq0.w;  y3 += b.w * wq1.w;
            }
            if (v0) unsafeAtomicAdd(out + (size_t)fl0[a0] * COUT + ch, (x0 + x1) + (x2 + x3));
            if (v1) unsafeAtomicAdd(out + (size_t)fl1[a1] * COUT + ch, (y0 + y1) + (y2 + y3));
        }
    }
}

// ---------- fallback (ws too small for even W): round-1 scatter ----------
__global__ __launch_bounds__(256, 4) void spconv_scatter(
    const float* __restrict__ feats, const float* __restrict__ Wt,
    const int* __restrict__ coors, float* __restrict__ out, int N)
{
    __shared__ float sf[NPTS][CIN];
    __shared__ int   sc[NPTS][4];
    __shared__ int   vf[NPTS];

    const int tid = threadIdx.x;
    const int ch  = tid & 63;
    const int wv  = tid >> 6;
    const int base = blockIdx.x * NPTS;
    const int npts = min(NPTS, (int)(N - base));
    if (npts <= 0) return;

    for (int i = tid; i < npts * CIN; i += 256) sf[0][i] = feats[base * CIN + i];
    for (int i = tid; i < npts * 4; i += 256) ((int*)sc)[i] = coors[base * 4 + i];
    __syncthreads();

    for (int off = 0; off < 27; ++off) {
        const int kz = off / 9, ky = (off / 3) % 3, kx = off % 3;
        if (tid < npts) {
            const int p  = tid;
            const int nz = sc[p][1] + 1 - kz;
            const int ny = sc[p][2] + 1 - ky;
            const int nx = sc[p][3] + 1 - kx;
            const int m  = nz | ny | nx;
            const int oz = nz >> 1, oy = ny >> 1, ox = nx >> 1;
            const bool v = ((m & 0x80000001) == 0) &&
                           (oz < OUTD) && (oy < OUTD) && (ox < OUTD);
            vf[p] = v ? (((sc[p][0] * OUTD + oz) * OUTD + oy) * OUTD + ox) : -1;
        }
        const float* wp = Wt + off * (CIN * COUT) + ch;
        float w[CIN];
        #pragma unroll
        for (int c = 0; c < CIN; ++c) w[c] = wp[c * COUT];
        __syncthreads();
        for (int p = wv; p < npts; p += 4) {
            const int f = vf[p];
            if (f >= 0) {
                float s = 0.f;
                #pragma unroll
                for (int c = 0; c < CIN; ++c) s += sf[p][c] * w[c];
                atomicAdd(&out[(size_t)f * COUT + ch], s);
            }
        }
        __syncthreads();
    }
}

extern "C" void kernel_launch(void* const* d_in, const int* in_sizes, int n_in,
                              void* d_out, int out_size, void* d_ws, size_t ws_size,
                              hipStream_t stream) {
    const float* feats = (const float*)d_in[0];
    const float* Wt    = (const float*)d_in[1];
    const int*   coors = (const int*)d_in[2];
    float*       out   = (float*)d_out;

    const int N = in_sizes[0] / CIN;

    hipMemsetAsync(d_out, 0, (size_t)out_size * sizeof(float), stream);

    const size_t need = 27 * CIN * COUT * sizeof(float);
    if (ws_size >= need) {
        float* wsW = (float*)d_ws;
        conv_w_t<<<27, 256, 0, stream>>>(Wt, wsW);
        scatter5<<<NBLK, 256, 0, stream>>>(feats, wsW, (const int4*)coors, out, N, NBLK * 4);
    } else {
        spconv_scatter<<<(N + NPTS - 1) / NPTS, 256, 0, stream>>>(feats, Wt, coors, out, N);
    }
}

// Round 10
// 407.434 us; speedup vs baseline: 1.0942x; 1.0942x over previous
//
#include <hip/hip_runtime.h>

// Sparse 3D conv (K=3, stride=2, pad=1), dense output, direct per-point scatter.
// Persistent grid (2048 blocks); one wave per point; 64 lanes = 64 out channels;
// <=8 posted global atomics per point. W pre-transposed to [27][64][32] f32.
// Inputs: features [N,32] f32, W [3,3,3,32,64] f32, coors [N,4] i32 (b,z,y,x).
// Output: [B,64,64,64,64] f32 flat (memset to 0, then posted atomic adds).
// ws: [ W_t 27*64*32 f32 ]  (~221 KB)

#define CIN   32
#define COUT  64
#define OUTD  64
#define NBLK  2048
#define NPTS  128

// Valid (k, o) options along one axis: o = (p+1-k)/2, parity-matched, 0<=o<64.
// Arrays are only ever indexed by the 2-bounded loop vars below -> registers.
__device__ __forceinline__ int axis_opts(int p, int* k, int* o) {
    int cnt = 0;
    const int kp = (p + 1) & 1;          // smallest parity-matching k
    const int o0 = (p + 1 - kp) >> 1;    // >= 0 always
    if (o0 < OUTD) { k[cnt] = kp; o[cnt] = o0; ++cnt; }
    if (kp == 0) {                       // k=2 shares parity with k=0
        const int o1 = o0 - 1;
        if (o1 >= 0) { k[cnt] = 2; o[cnt] = o1; ++cnt; }
    }
    return cnt;
}

// ---------- W transpose: [27][32][64] -> [27][64][32], f32 ----------
__global__ void conv_w_t(const float* __restrict__ W, float* __restrict__ wsW)
{
    const int k = blockIdx.x;            // 27 blocks
    for (int i = threadIdx.x; i < CIN * COUT; i += 256) {
        const int c = i >> 6, ch = i & 63;     // read coalesced over i
        wsW[(k << 11) + (ch << 5) + c] = W[(k << 11) + i];
    }
}

// ---------- scatter: persistent waves, one point per iteration ----------
__global__ __launch_bounds__(256) void scatter6(
    const float* __restrict__ feats, const float* __restrict__ wsW,
    const int4* __restrict__ coors, float* __restrict__ out,
    int N, int totWaves)
{
    const int ch = threadIdx.x & 63;
    const int wv = threadIdx.x >> 6;
    const int gwave = blockIdx.x * 4 + wv;

    for (int i = gwave; i < N; i += totWaves) {
        const int4 c = coors[i];                         // wave-uniform
        const float4* fp = (const float4*)(feats + (size_t)i * CIN);
        float4 f[8];
        #pragma unroll
        for (int q = 0; q < 8; ++q) f[q] = fp[q];        // broadcast row

        int kz[2], oz[2], ky[2], oy[2], kx[2], ox[2];
        const int nz = axis_opts(c.y, kz, oz);
        const int ny = axis_opts(c.z, ky, oy);
        const int nx = axis_opts(c.w, kx, ox);

        for (int az = 0; az < nz; ++az)
        for (int ay = 0; ay < ny; ++ay)
        for (int ax = 0; ax < nx; ++ax) {
            const int kidx = (kz[az] * 3 + ky[ay]) * 3 + kx[ax];
            const float4* wp = (const float4*)(wsW + (kidx << 11) + (ch << 5));
            // float2 accumulator pairs -> v_pk_fma_f32-friendly, 4 indep chains
            float2 sA = make_float2(0.f, 0.f), sB = make_float2(0.f, 0.f);
            #pragma unroll
            for (int q = 0; q < 8; ++q) {
                const float4 wq = wp[q];
                const float4 fq = f[q];
                sA.x += fq.x * wq.x;
                sA.y += fq.y * wq.y;
                sB.x += fq.z * wq.z;
                sB.y += fq.w * wq.w;
            }
            const size_t flat = (((size_t)c.x * OUTD + oz[az]) * OUTD + oy[ay]) * OUTD + ox[ax];
            unsafeAtomicAdd(out + flat * COUT + ch, (sA.x + sA.y) + (sB.x + sB.y));  // posted
        }
    }
}

// ---------- fallback (ws too small for even W): round-1 scatter ----------
__global__ __launch_bounds__(256, 4) void spconv_scatter(
    const float* __restrict__ feats, const float* __restrict__ Wt,
    const int* __restrict__ coors, float* __restrict__ out, int N)
{
    __shared__ float sf[NPTS][CIN];
    __shared__ int   sc[NPTS][4];
    __shared__ int   vf[NPTS];

    const int tid = threadIdx.x;
    const int ch  = tid & 63;
    const int wv  = tid >> 6;
    const int base = blockIdx.x * NPTS;
    const int npts = min(NPTS, (int)(N - base));
    if (npts <= 0) return;

    for (int i = tid; i < npts * CIN; i += 256) sf[0][i] = feats[base * CIN + i];
    for (int i = tid; i < npts * 4; i += 256) ((int*)sc)[i] = coors[base * 4 + i];
    __syncthreads();

    for (int off = 0; off < 27; ++off) {
        const int kz = off / 9, ky = (off / 3) % 3, kx = off % 3;
        if (tid < npts) {
            const int p  = tid;
            const int nz = sc[p][1] + 1 - kz;
            const int ny = sc[p][2] + 1 - ky;
            const int nx = sc[p][3] + 1 - kx;
            const int m  = nz | ny | nx;
            const int oz = nz >> 1, oy = ny >> 1, ox = nx >> 1;
            const bool v = ((m & 0x80000001) == 0) &&
                           (oz < OUTD) && (oy < OUTD) && (ox < OUTD);
            vf[p] = v ? (((sc[p][0] * OUTD + oz) * OUTD + oy) * OUTD + ox) : -1;
        }
        const float* wp = Wt + off * (CIN * COUT) + ch;
        float w[CIN];
        #pragma unroll
        for (int c = 0; c < CIN; ++c) w[c] = wp[c * COUT];
        __syncthreads();
        for (int p = wv; p < npts; p += 4) {
            const int f = vf[p];
            if (f >= 0) {
                float s = 0.f;
                #pragma unroll
                for (int c = 0; c < CIN; ++c) s += sf[p][c] * w[c];
                atomicAdd(&out[(size_t)f * COUT + ch], s);
            }
        }
        __syncthreads();
    }
}

extern "C" void kernel_launch(void* const* d_in, const int* in_sizes, int n_in,
                              void* d_out, int out_size, void* d_ws, size_t ws_size,
                              hipStream_t stream) {
    const float* feats = (const float*)d_in[0];
    const float* Wt    = (const float*)d_in[1];
    const int*   coors = (const int*)d_in[2];
    float*       out   = (float*)d_out;

    const int N = in_sizes[0] / CIN;

    hipMemsetAsync(d_out, 0, (size_t)out_size * sizeof(float), stream);

    const size_t need = 27 * CIN * COUT * sizeof(float);
    if (ws_size >= need) {
        float* wsW = (float*)d_ws;
        conv_w_t<<<27, 256, 0, stream>>>(Wt, wsW);
        scatter6<<<NBLK, 256, 0, stream>>>(feats, wsW, (const int4*)coors, out, N, NBLK * 4);
    } else {
        spconv_scatter<<<(N + NPTS - 1) / NPTS, 256, 0, stream>>>(feats, Wt, coors, out, N);
    }
}

// Round 11
// 164.230 us; speedup vs baseline: 2.7145x; 2.4809x over previous
//
#include <hip/hip_runtime.h>

// Sparse 3D conv (K=3, stride=2, pad=1), dense output.
// k-major bucketed scatter: pairs binned by kernel-offset; scatter waves hold
// the W column for their bucket in REGISTERS (coalesced load, amortized over a
// 32-pair chunk), so per-pair memory traffic is ~1 pair load + 8 broadcast
// feats loads + 1 posted atomic line.
// Inputs: features [N,32] f32, W [3,3,3,32,64] f32, coors [N,4] i32 (b,z,y,x).
// Output: [B,64,64,64,64] f32 flat (memset 0 + posted atomic adds).
// ws: [ cursors 32 i32 | buckets 27 * 32768 * int2 ]  (~7.1 MB)

#define CIN    32
#define COUT   64
#define OUTD   64
#define NBLK   2048
#define NPTS   128
#define BCAP   32768      // per-kidx bucket capacity (mean ~12.5K)
#define BINCAP 96         // per-block per-kidx LDS capacity (mean 32)
#define CH     32         // pairs per scatter chunk
#define NK     27

// Valid (k, o) options along one axis: o = (p+1-k)/2, parity-matched, 0<=o<64.
__device__ __forceinline__ int axis_opts(int p, int* k, int* o) {
    int cnt = 0;
    const int kp = (p + 1) & 1;          // smallest parity-matching k
    const int o0 = (p + 1 - kp) >> 1;    // >= 0 always
    if (o0 < OUTD) { k[cnt] = kp; o[cnt] = o0; ++cnt; }
    if (kp == 0) {                       // k=2 shares parity with k=0
        const int o1 = o0 - 1;
        if (o1 >= 0) { k[cnt] = 2; o[cnt] = o1; ++cnt; }
    }
    return cnt;
}

// ---------- binning: block-local LDS histogram -> bucketed pair lists ----------
__global__ __launch_bounds__(256) void bin_pairs(
    const int4* __restrict__ coors, int* __restrict__ gcur,
    int2* __restrict__ pairs, int N)
{
    __shared__ int cntk[NK];
    __shared__ int basek[NK];
    __shared__ int li[NK * BINCAP];
    __shared__ int lf[NK * BINCAP];

    const int tid = threadIdx.x;
    if (tid < NK) cntk[tid] = 0;
    __syncthreads();

    const int i = blockIdx.x * 256 + tid;
    if (i < N) {
        const int4 c = coors[i];
        int kz[2], oz[2], ky[2], oy[2], kx[2], ox[2];
        const int nz = axis_opts(c.y, kz, oz);
        const int ny = axis_opts(c.z, ky, oy);
        const int nx = axis_opts(c.w, kx, ox);
        for (int az = 0; az < nz; ++az)
        for (int ay = 0; ay < ny; ++ay)
        for (int ax = 0; ax < nx; ++ax) {
            const int kidx = (kz[az] * 3 + ky[ay]) * 3 + kx[ax];
            const int flat = ((c.x * OUTD + oz[az]) * OUTD + oy[ay]) * OUTD + ox[ax];
            const int slot = atomicAdd(&cntk[kidx], 1);
            if (slot < BINCAP) {
                li[kidx * BINCAP + slot] = i;
                lf[kidx * BINCAP + slot] = flat;
            } else {                       // statistically ~never
                const int pos = atomicAdd(&gcur[kidx], 1);
                pairs[(size_t)kidx * BCAP + pos] = make_int2(i, flat);
            }
        }
    }
    __syncthreads();
    if (tid < NK) basek[tid] = atomicAdd(&gcur[tid], min(cntk[tid], BINCAP));
    __syncthreads();

    for (int k = 0; k < NK; ++k) {
        const int m = min(cntk[k], BINCAP);
        const int base = basek[k];
        for (int e = tid; e < m; e += 256)
            pairs[(size_t)k * BCAP + base + e] = make_int2(li[k * BINCAP + e], lf[k * BINCAP + e]);
    }
}

// ---------- scatter: persistent waves, W column in registers per chunk ----------
__global__ __launch_bounds__(256) void scatter_k(
    const float* __restrict__ feats, const float* __restrict__ W,
    const int* __restrict__ gcur, const int2* __restrict__ pairs,
    float* __restrict__ out, int totWaves)
{
    const int ch = threadIdx.x & 63;
    const int wv = threadIdx.x >> 6;
    const int gwave = blockIdx.x * 4 + wv;

    for (int v = gwave; ; v += totWaves) {
        // map virtual chunk v -> (bucket selk, offset seloff); fully unrolled scan
        int rem = v, selk = -1, seloff = 0, selcnt = 0;
        #pragma unroll
        for (int k = 0; k < NK; ++k) {
            const int cnt = gcur[k];                 // uniform, L2/L1-hot
            const int ck  = (cnt + CH - 1) >> 5;     // chunks in bucket k
            if (selk < 0) {
                if (rem < ck) { selk = k; seloff = rem << 5; selcnt = cnt; }
                else rem -= ck;
            }
        }
        if (selk < 0) break;                         // past last chunk: done

        // W column for this bucket: W[selk][c][ch], 4B lane stride = coalesced
        const float* wp = W + (selk << 11) + ch;
        float w[CIN];
        #pragma unroll
        for (int c = 0; c < CIN; ++c) w[c] = wp[c << 6];

        const int m = min(CH, selcnt - seloff);
        const int2* pb = pairs + (size_t)selk * BCAP + seloff;
        for (int e = 0; e < m; ++e) {
            const int2 pr = pb[e];                   // wave-uniform 8B load
            const float4* fp = (const float4*)(feats + (size_t)pr.x * CIN);
            float4 f[8];
            #pragma unroll
            for (int q = 0; q < 8; ++q) f[q] = fp[q];    // broadcast row
            float s0 = 0.f, s1 = 0.f, s2 = 0.f, s3 = 0.f;
            #pragma unroll
            for (int q = 0; q < 8; ++q) {
                const float4 fq = f[q];
                s0 += fq.x * w[4 * q + 0];
                s1 += fq.y * w[4 * q + 1];
                s2 += fq.z * w[4 * q + 2];
                s3 += fq.w * w[4 * q + 3];
            }
            unsafeAtomicAdd(out + (size_t)pr.y * COUT + ch, (s0 + s1) + (s2 + s3));
        }
    }
}

// ---------- secondary path (R7 champion, needs only 110 KB ws) ----------
__global__ void conv_w_bf16(const float* __restrict__ W, ushort* __restrict__ wsW)
{
    const int k = blockIdx.x;
    for (int i = threadIdx.x; i < CIN * COUT; i += 256) {
        const int c = i >> 6, ch = i & 63;
        const unsigned u = __float_as_uint(W[k * CIN * COUT + i]);
        const unsigned r = (u + 0x7fffu + ((u >> 16) & 1u)) >> 16;   // RNE
        wsW[(k << 11) + (ch << 5) + c] = (ushort)r;
    }
}

__global__ __launch_bounds__(256) void scatter2(
    const float* __restrict__ feats, const ushort* __restrict__ wsW,
    const int4* __restrict__ coors, float* __restrict__ out,
    int N, int totWaves)
{
    const int ch = threadIdx.x & 63;
    const int wv = __builtin_amdgcn_readfirstlane(threadIdx.x >> 6);
    const int gwave = blockIdx.x * 4 + wv;

    for (int i = gwave; i < N; i += totWaves) {
        const int4 c = coors[i];
        const float4* fp = (const float4*)(feats + (size_t)i * CIN);
        float4 f[8];
        #pragma unroll
        for (int q = 0; q < 8; ++q) f[q] = fp[q];

        int kz[2], oz[2], ky[2], oy[2], kx[2], ox[2];
        const int nz = axis_opts(c.y, kz, oz);
        const int ny = axis_opts(c.z, ky, oy);
        const int nx = axis_opts(c.w, kx, ox);

        for (int az = 0; az < nz; ++az)
        for (int ay = 0; ay < ny; ++ay)
        for (int ax = 0; ax < nx; ++ax) {
            const int kidx = (kz[az] * 3 + ky[ay]) * 3 + kx[ax];
            const uint4* wp = (const uint4*)(wsW + (kidx << 11) + (ch << 5));
            uint4 w4[4];
            #pragma unroll
            for (int q = 0; q < 4; ++q) w4[q] = wp[q];
            float s0 = 0.f, s1 = 0.f;
            #pragma unroll
            for (int q = 0; q < 4; ++q) {
                const uint4 wq = w4[q];
                const float4 fa = f[2 * q], fb = f[2 * q + 1];
                s0 += fa.x * __uint_as_float(wq.x << 16);
                s1 += fa.y * __uint_as_float(wq.x & 0xffff0000u);
                s0 += fa.z * __uint_as_float(wq.y << 16);
                s1 += fa.w * __uint_as_float(wq.y & 0xffff0000u);
                s0 += fb.x * __uint_as_float(wq.z << 16);
                s1 += fb.y * __uint_as_float(wq.z & 0xffff0000u);
                s0 += fb.z * __uint_as_float(wq.w << 16);
                s1 += fb.w * __uint_as_float(wq.w & 0xffff0000u);
            }
            const size_t flat = (((size_t)c.x * OUTD + oz[az]) * OUTD + oy[ay]) * OUTD + ox[ax];
            unsafeAtomicAdd(out + flat * COUT + ch, s0 + s1);
        }
    }
}

// ---------- last-resort fallback ----------
__global__ __launch_bounds__(256, 4) void spconv_scatter(
    const float* __restrict__ feats, const float* __restrict__ Wt,
    const int* __restrict__ coors, float* __restrict__ out, int N)
{
    __shared__ float sf[NPTS][CIN];
    __shared__ int   sc[NPTS][4];
    __shared__ int   vf[NPTS];

    const int tid = threadIdx.x;
    const int ch  = tid & 63;
    const int wv  = tid >> 6;
    const int base = blockIdx.x * NPTS;
    const int npts = min(NPTS, (int)(N - base));
    if (npts <= 0) return;

    for (int i = tid; i < npts * CIN; i += 256) sf[0][i] = feats[base * CIN + i];
    for (int i = tid; i < npts * 4; i += 256) ((int*)sc)[i] = coors[base * 4 + i];
    __syncthreads();

    for (int off = 0; off < 27; ++off) {
        const int kz = off / 9, ky = (off / 3) % 3, kx = off % 3;
        if (tid < npts) {
            const int p  = tid;
            const int nz = sc[p][1] + 1 - kz;
            const int ny = sc[p][2] + 1 - ky;
            const int nx = sc[p][3] + 1 - kx;
            const int m  = nz | ny | nx;
            const int oz = nz >> 1, oy = ny >> 1, ox = nx >> 1;
            const bool v = ((m & 0x80000001) == 0) &&
                           (oz < OUTD) && (oy < OUTD) && (ox < OUTD);
            vf[p] = v ? (((sc[p][0] * OUTD + oz) * OUTD + oy) * OUTD + ox) : -1;
        }
        const float* wp = Wt + off * (CIN * COUT) + ch;
        float w[CIN];
        #pragma unroll
        for (int c = 0; c < CIN; ++c) w[c] = wp[c * COUT];
        __syncthreads();
        for (int p = wv; p < npts; p += 4) {
            const int f = vf[p];
            if (f >= 0) {
                float s = 0.f;
                #pragma unroll
                for (int c = 0; c < CIN; ++c) s += sf[p][c] * w[c];
                atomicAdd(&out[(size_t)f * COUT + ch], s);
            }
        }
        __syncthreads();
    }
}

extern "C" void kernel_launch(void* const* d_in, const int* in_sizes, int n_in,
                              void* d_out, int out_size, void* d_ws, size_t ws_size,
                              hipStream_t stream) {
    const float* feats = (const float*)d_in[0];
    const float* Wt    = (const float*)d_in[1];
    const int*   coors = (const int*)d_in[2];
    float*       out   = (float*)d_out;

    const int N = in_sizes[0] / CIN;

    hipMemsetAsync(d_out, 0, (size_t)out_size * sizeof(float), stream);

    const size_t needK = 32 * sizeof(int) + (size_t)NK * BCAP * sizeof(int2);
    const size_t needB = 27 * CIN * COUT * sizeof(ushort);

    if (ws_size >= needK) {
        int*  gcur  = (int*)d_ws;
        int2* pairs = (int2*)((char*)d_ws + 32 * sizeof(int));
        hipMemsetAsync(gcur, 0, 32 * sizeof(int), stream);
        bin_pairs<<<(N + 255) / 256, 256, 0, stream>>>((const int4*)coors, gcur, pairs, N);
        scatter_k<<<NBLK, 256, 0, stream>>>(feats, Wt, gcur, pairs, out, NBLK * 4);
    } else if (ws_size >= needB) {
        ushort* wsW = (ushort*)d_ws;
        conv_w_bf16<<<27, 256, 0, stream>>>(Wt, wsW);
        scatter2<<<NBLK, 256, 0, stream>>>(feats, wsW, (const int4*)coors, out, N, NBLK * 4);
    } else {
        spconv_scatter<<<(N + NPTS - 1) / NPTS, 256, 0, stream>>>(feats, Wt, coors, out, N);
    }
}